// Round 7
// baseline (113.006 us; speedup 1.0000x reference)
//
#include <hip/hip_runtime.h>
#include <math.h>

#define E_CNT 1999
#define N_PTS 2000
#define B_CNT 8
#define SEG 2048                           // X edges in [0,SEG), target edges in [SEG,2*SEG)
#define MPAD (2*SEG)                       // 4096 padded combined edges
#define NTILES 16                          // 256-row tiles
#define NTP 136                            // upper-triangle tile pairs
#define PAIR_BLOCKS (B_CNT*NTP)            // 1088
#define PRE_BLOCKS  (B_CNT*16)             // 128
#define NPART (PAIR_BLOCKS + PRE_BLOCKS)   // 1216
#define REP 5                              // diagnostic work multiplier
#define RSCALE 0.2f                        // 1/REP

#define HCEXP (-2.8853900817779268f)       // -2*log2(e)
#define NEG2C (11.541560327111707f)        // +8*log2(e)

// Per edge slot s of sample b:
//   eA[b*MPAD+s] = (cx, cy, cz, u''x),  eB[b*MPAD+s] = (u''y, u''z)
// where u'' = (t/sqrt(l)) * exp2(HCEXP*|c|^2).  Pads all-zero.
__global__ __launch_bounds__(256) void pre_kernel(
    const float* __restrict__ outp, const float* __restrict__ tgtp,
    const float* __restrict__ tmpl, float4* __restrict__ eA,
    float2* __restrict__ eB, float* __restrict__ part)
{
    int b = blockIdx.x >> 4;
    int p = ((blockIdx.x & 15) << 8) + threadIdx.x;   // 0..4095

    float val = 0.f;
    float4 A = make_float4(0.f, 0.f, 0.f, 0.f);
    float2 Bv = make_float2(0.f, 0.f);

    bool isX = (p < SEG);
    int e = isX ? p : p - SEG;
    if (e < E_CNT) {
        float ax, ay, az, bx, by, bz;
        if (isX) {
            const float* o0 = outp + ((size_t)b * N_PTS + e) * 3;
            const float* t0 = tmpl + (size_t)e * 3;
            ax = o0[0] + t0[0]; ay = o0[1] + t0[1]; az = o0[2] + t0[2];
            bx = o0[3] + t0[3]; by = o0[4] + t0[4]; bz = o0[5] + t0[5];
        } else {
            const float* g0 = tgtp + ((size_t)b * N_PTS + e) * 3;
            ax = g0[0]; ay = g0[1]; az = g0[2];
            bx = g0[3]; by = g0[4]; bz = g0[5];
        }
        float cx = 0.5f * (ax + bx), cy = 0.5f * (ay + by), cz = 0.5f * (az + bz);
        float tx = bx - ax, ty = by - ay, tz = bz - az;
        float l2 = tx * tx + ty * ty + tz * tz + 1e-12f;
        float l  = sqrtf(l2);
        float rs = rsqrtf(l);
        float f  = __builtin_amdgcn_exp2f(HCEXP * (cx * cx + cy * cy + cz * cz));
        float g  = rs * f;
        A  = make_float4(cx, cy, cz, tx * g);
        Bv = make_float2(ty * g, tz * g);
        val = l * l;
        if (isX) {
            const float* t0 = tmpl + (size_t)e * 3;
            float txT = t0[3] - t0[0], tyT = t0[4] - t0[1], tzT = t0[5] - t0[2];
            float lT = sqrtf(txT * txT + tyT * tyT + tzT * tzT + 1e-12f);
            float rT = rsqrtf(lT);
            float dqx = tx * rs - txT * rT;
            float dqy = ty * rs - tyT * rT;
            float dqz = tz * rs - tzT * rT;
            val += 1e-7f * (dqx * dqx + dqy * dqy + dqz * dqz);
        }
    }
    size_t s = (size_t)b * MPAD + p;
    eA[s] = A;
    eB[s] = Bv;

    for (int off = 32; off; off >>= 1) val += __shfl_down(val, off);
    __shared__ float red[4];
    int lane = threadIdx.x & 63, wid = threadIdx.x >> 6;
    if (lane == 0) red[wid] = val;
    __syncthreads();
    if (threadIdx.x == 0)
        part[PAIR_BLOCKS + blockIdx.x] = (red[0] + red[1]) + (red[2] + red[3]);
}

// DIAGNOSTIC build: inner loop repeated REP times (result scaled by 1/REP)
// so pair_kernel's duration rises above the harness fill dispatches and its
// counters (VALUBusy / Occupancy / LDS conflicts) become visible in top-5.
__global__ __launch_bounds__(256) void pair_kernel(
    const float4* __restrict__ eA, const float2* __restrict__ eB,
    float* __restrict__ part)
{
    __shared__ float4 sA[256];
    __shared__ float2 sB[256];
    __shared__ float  red[4];

    int id = blockIdx.x;
    int b = id / NTP;
    int t = id % NTP;
    int rt = 0, rem = t;
    while (rem >= NTILES - rt) { rem -= NTILES - rt; ++rt; }
    int ct = rt + rem;

    int tid = threadIdx.x, lane = tid & 63, w = tid >> 6;
    const float4* __restrict__ ebA = eA + (size_t)b * MPAD;
    const float2* __restrict__ ebB = eB + (size_t)b * MPAD;

    {
        int cj = ct * 256 + tid;
        sA[tid] = ebA[cj];
        sB[tid] = ebB[cj];
    }

    float chx[4], chy[4], chz[4], rux[4], ruy[4], ruz[4];
    int ri[4];
    #pragma unroll
    for (int k = 0; k < 4; ++k) {
        int i = rt * 256 + k * 64 + lane;
        ri[k] = i;
        float4 A = ebA[i];
        float2 Bv = ebB[i];
        chx[k] = NEG2C * A.x; chy[k] = NEG2C * A.y; chz[k] = NEG2C * A.z;
        rux[k] = A.w; ruy[k] = Bv.x; ruz[k] = Bv.y;
    }
    __syncthreads();

    float av[4] = {0.f, 0.f, 0.f, 0.f};
    int jl0 = w * 64;
    int j0  = ct * 256 + jl0;

    for (int rep = 0; rep < REP; ++rep) {
        if (rt != ct) {
            float4 a0 = sA[jl0];
            float2 b0 = sB[jl0];
            #pragma unroll 4
            for (int jj = 0; jj < 63; ++jj) {
                float4 a1 = sA[jl0 + jj + 1];
                float2 b1 = sB[jl0 + jj + 1];
                #pragma unroll
                for (int k = 0; k < 4; ++k) {
                    float arg = chx[k] * a0.x;
                    arg = fmaf(chy[k], a0.y, arg);
                    arg = fmaf(chz[k], a0.z, arg);
                    float E = __builtin_amdgcn_exp2f(arg);
                    float du = rux[k] * a0.w;
                    du = fmaf(ruy[k], b0.x, du);
                    du = fmaf(ruz[k], b0.y, du);
                    av[k] = fmaf(E, du * du, av[k]);
                }
                a0 = a1; b0 = b1;
            }
            #pragma unroll
            for (int k = 0; k < 4; ++k) {
                float arg = chx[k] * a0.x;
                arg = fmaf(chy[k], a0.y, arg);
                arg = fmaf(chz[k], a0.z, arg);
                float E = __builtin_amdgcn_exp2f(arg);
                float du = rux[k] * a0.w;
                du = fmaf(ruy[k], b0.x, du);
                du = fmaf(ruz[k], b0.y, du);
                av[k] = fmaf(E, du * du, av[k]);
            }
        } else {
            float4 a0 = sA[jl0];
            float2 b0 = sB[jl0];
            #pragma unroll 4
            for (int jj = 0; jj < 64; ++jj) {
                float4 a1 = sA[(jl0 + jj + 1) & 255];
                float2 b1 = sB[(jl0 + jj + 1) & 255];
                int j = j0 + jj;
                #pragma unroll
                for (int k = 0; k < 4; ++k) {
                    float arg = chx[k] * a0.x;
                    arg = fmaf(chy[k], a0.y, arg);
                    arg = fmaf(chz[k], a0.z, arg);
                    float E = __builtin_amdgcn_exp2f(arg);
                    float du = rux[k] * a0.w;
                    du = fmaf(ruy[k], b0.x, du);
                    du = fmaf(ruz[k], b0.y, du);
                    float m = (j > ri[k]) ? du * du : 0.f;
                    av[k] = fmaf(E, m, av[k]);
                }
                a0 = a1; b0 = b1;
            }
        }
    }

    float sgn = ((rt < 8) == (ct < 8)) ? 2.f : -2.f;
    float thr = sgn * RSCALE * ((av[0] + av[1]) + (av[2] + av[3]));
    for (int off = 32; off; off >>= 1) thr += __shfl_down(thr, off);
    if (lane == 0) red[w] = thr;
    __syncthreads();
    if (tid == 0)
        part[id] = (red[0] + red[1]) + (red[2] + red[3]);
}

__global__ __launch_bounds__(256) void final_kernel(
    const float* __restrict__ part, float* __restrict__ outv)
{
    float s = 0.f;
    for (int i = threadIdx.x; i < NPART; i += 256) s += part[i];
    for (int off = 32; off; off >>= 1) s += __shfl_down(s, off);
    __shared__ float red[4];
    int lane = threadIdx.x & 63, wid = threadIdx.x >> 6;
    if (lane == 0) red[wid] = s;
    __syncthreads();
    if (threadIdx.x == 0)
        outv[0] = 0.125f * ((red[0] + red[1]) + (red[2] + red[3]));
}

extern "C" void kernel_launch(void* const* d_in, const int* in_sizes, int n_in,
                              void* d_out, int out_size, void* d_ws, size_t ws_size,
                              hipStream_t stream)
{
    const float* outp = (const float*)d_in[0];  // (8,2000,3) f32
    const float* tgtp = (const float*)d_in[1];  // (8,2000,3) f32
    const float* tmpl = (const float*)d_in[3];  // (2000,3) f32
    float*  part = (float*)d_ws;                             // 1216 floats
    float4* eA   = (float4*)((char*)d_ws + 65536);           // 512 KiB
    float2* eB   = (float2*)((char*)d_ws + 65536 + 524288);  // 256 KiB

    pre_kernel<<<PRE_BLOCKS, 256, 0, stream>>>(outp, tgtp, tmpl, eA, eB, part);
    pair_kernel<<<PAIR_BLOCKS, 256, 0, stream>>>(eA, eB, part);
    final_kernel<<<1, 256, 0, stream>>>(part, (float*)d_out);
}

// Round 9
// 72.898 us; speedup vs baseline: 1.5502x; 1.5502x over previous
//
#include <hip/hip_runtime.h>
#include <math.h>

#define E_CNT 1999
#define N_PTS 2000
#define B_CNT 8
#define SEG 2048                           // X edges in [0,SEG), target edges in [SEG,2*SEG)
#define NTILES 16                          // 256-row tiles
#define NTP 136                            // upper-triangle tile pairs
#define NCH 2                              // 128-col chunks per 256-col tile
#define BLOCKS_PER_B (NTP*NCH)             // 272
#define TOTAL_BLOCKS (B_CNT*BLOCKS_PER_B)  // 2176

#define HCEXP (-2.8853900817779268f)       // -2*log2(e)
#define NEG2C (11.541560327111707f)        // +8*log2(e)

// Generate combined-edge data for slot in [0,2*SEG) of sample b:
//   A = (cx, cy, cz, u''x),  Bv = (u''y, u''z),  u'' = (t/sqrt(l)) * exp2(HCEXP*|c|^2)
// Returns diag contribution (l^2 [+ SRNF for X edges]) when wantDiag.
__device__ __forceinline__ float edge_gen(
    const float* __restrict__ outp, const float* __restrict__ tgtp,
    const float* __restrict__ tmpl, int b, int slot, bool wantDiag,
    float4& A, float2& Bv)
{
    A = make_float4(0.f, 0.f, 0.f, 0.f);
    Bv = make_float2(0.f, 0.f);
    float val = 0.f;
    bool isX = (slot < SEG);
    int e = isX ? slot : slot - SEG;
    if (e < E_CNT) {
        float ax, ay, az, bx, by, bz;
        if (isX) {
            const float* o0 = outp + ((size_t)b * N_PTS + e) * 3;
            const float* t0 = tmpl + (size_t)e * 3;
            ax = o0[0] + t0[0]; ay = o0[1] + t0[1]; az = o0[2] + t0[2];
            bx = o0[3] + t0[3]; by = o0[4] + t0[4]; bz = o0[5] + t0[5];
        } else {
            const float* g0 = tgtp + ((size_t)b * N_PTS + e) * 3;
            ax = g0[0]; ay = g0[1]; az = g0[2];
            bx = g0[3]; by = g0[4]; bz = g0[5];
        }
        float cx = 0.5f * (ax + bx), cy = 0.5f * (ay + by), cz = 0.5f * (az + bz);
        float tx = bx - ax, ty = by - ay, tz = bz - az;
        float l2 = tx * tx + ty * ty + tz * tz + 1e-12f;
        float l  = sqrtf(l2);
        float rs = rsqrtf(l);
        float f  = __builtin_amdgcn_exp2f(HCEXP * (cx * cx + cy * cy + cz * cz));
        float g  = rs * f;
        A  = make_float4(cx, cy, cz, tx * g);
        Bv = make_float2(ty * g, tz * g);
        if (wantDiag) {
            val = l * l;
            if (isX) {
                const float* t0 = tmpl + (size_t)e * 3;
                float txT = t0[3] - t0[0], tyT = t0[4] - t0[1], tzT = t0[5] - t0[2];
                float lT = sqrtf(txT * txT + tyT * tyT + tzT * tzT + 1e-12f);
                float rT = rsqrtf(lT);
                float dqx = tx * rs - txT * rT;     // q = t/sqrt(l)
                float dqy = ty * rs - tyT * rT;
                float dqz = tz * rs - tzT * rT;
                val += 1e-7f * (dqx * dqx + dqy * dqy + dqz * dqz);
            }
        }
    }
    return val;
}

// Fully fused: edge-gen prologue + strict-upper-triangle pair sum + diag/SRNF
// (wave 0 of rt==ct, ch==0 blocks ONLY — R8 bug was all 4 waves adding it) +
// last-block finalize.  Block = 256 rows x 128 cols; 4 waves split columns
// (32 each); each lane owns 4 rows (R=4).
// ws layout: acc[0] = float accumulator, acc[1] = uint completion counter.
__global__ __launch_bounds__(256) void fused_kernel(
    const float* __restrict__ outp, const float* __restrict__ tgtp,
    const float* __restrict__ tmpl, float* __restrict__ acc,
    float* __restrict__ outv)
{
    __shared__ float4 sA[128];
    __shared__ float2 sB[128];
    __shared__ float  red[4];

    int id = blockIdx.x;
    int b  = id / BLOCKS_PER_B;
    int r  = id % BLOCKS_PER_B;
    int t  = r >> 1, ch = r & 1;
    int rt = 0, rem = t;
    while (rem >= NTILES - rt) { rem -= NTILES - rt; ++rt; }
    int ct = rt + rem;

    int tid = threadIdx.x, lane = tid & 63, w = tid >> 6;

    // stage this block's 128 columns (threads 0..127, one edge each)
    int j0 = ct * 256 + ch * 128;
    if (tid < 128) {
        float4 A; float2 Bv;
        edge_gen(outp, tgtp, tmpl, b, j0 + tid, false, A, Bv);
        sA[tid] = A;
        sB[tid] = Bv;
    }

    // 4 rows per lane (same rows for all 4 waves); diag/SRNF by wave 0 only
    bool wantDiag = (rt == ct) && (ch == 0) && (w == 0);
    float chx[4], chy[4], chz[4], rux[4], ruy[4], ruz[4];
    int ri[4];
    float dval = 0.f;
    #pragma unroll
    for (int k = 0; k < 4; ++k) {
        int i = rt * 256 + k * 64 + lane;
        ri[k] = i;
        float4 A; float2 Bv;
        dval += edge_gen(outp, tgtp, tmpl, b, i, wantDiag, A, Bv);
        chx[k] = NEG2C * A.x; chy[k] = NEG2C * A.y; chz[k] = NEG2C * A.z;
        rux[k] = A.w; ruy[k] = Bv.x; ruz[k] = Bv.y;
    }
    __syncthreads();

    float av[4] = {0.f, 0.f, 0.f, 0.f};
    int jl0 = w * 32;                 // this wave's 32-column slice

    if (rt != ct) {
        #pragma unroll 4
        for (int jj = 0; jj < 32; ++jj) {
            float4 a0 = sA[jl0 + jj];
            float2 b0 = sB[jl0 + jj];
            #pragma unroll
            for (int k = 0; k < 4; ++k) {
                float arg = chx[k] * a0.x;
                arg = fmaf(chy[k], a0.y, arg);
                arg = fmaf(chz[k], a0.z, arg);
                float E = __builtin_amdgcn_exp2f(arg);
                float du = rux[k] * a0.w;
                du = fmaf(ruy[k], b0.x, du);
                du = fmaf(ruz[k], b0.y, du);
                av[k] = fmaf(E, du * du, av[k]);
            }
        }
    } else {
        #pragma unroll 4
        for (int jj = 0; jj < 32; ++jj) {
            float4 a0 = sA[jl0 + jj];
            float2 b0 = sB[jl0 + jj];
            int j = j0 + jl0 + jj;
            #pragma unroll
            for (int k = 0; k < 4; ++k) {
                float arg = chx[k] * a0.x;
                arg = fmaf(chy[k], a0.y, arg);
                arg = fmaf(chz[k], a0.z, arg);
                float E = __builtin_amdgcn_exp2f(arg);
                float du = rux[k] * a0.w;
                du = fmaf(ruy[k], b0.x, du);
                du = fmaf(ruz[k], b0.y, du);
                float m = (j > ri[k]) ? du * du : 0.f;   // strict upper
                av[k] = fmaf(E, m, av[k]);
            }
        }
    }

    // sign: same-segment tiles +, cross-segment -; x2 for symmetry.
    // dval (diag l^2 + SRNF) is sign-free, added once per row globally.
    float sgn = ((rt < 8) == (ct < 8)) ? 2.f : -2.f;
    float thr = fmaf(sgn, (av[0] + av[1]) + (av[2] + av[3]), dval);
    for (int off = 32; off; off >>= 1) thr += __shfl_down(thr, off);
    if (lane == 0) red[w] = thr;
    __syncthreads();

    if (tid == 0) {
        float blocksum = (red[0] + red[1]) + (red[2] + red[3]);
        atomicAdd(&acc[0], blocksum);
        __threadfence();
        unsigned old = atomicAdd((unsigned*)(acc + 1), 1u);
        if (old == TOTAL_BLOCKS - 1) {      // last block finalizes
            __threadfence();
            outv[0] = 0.125f * *((volatile float*)acc);
        }
    }
}

extern "C" void kernel_launch(void* const* d_in, const int* in_sizes, int n_in,
                              void* d_out, int out_size, void* d_ws, size_t ws_size,
                              hipStream_t stream)
{
    const float* outp = (const float*)d_in[0];  // (8,2000,3) f32
    const float* tgtp = (const float*)d_in[1];  // (8,2000,3) f32
    const float* tmpl = (const float*)d_in[3];  // (2000,3) f32
    float* acc = (float*)d_ws;                  // [0]=sum, [1]=counter

    hipMemsetAsync(d_ws, 0, 8, stream);
    fused_kernel<<<TOTAL_BLOCKS, 256, 0, stream>>>(outp, tgtp, tmpl, acc, (float*)d_out);
}

// Round 10
// 28.879 us; speedup vs baseline: 3.9131x; 2.5242x over previous
//
#include <hip/hip_runtime.h>
#include <math.h>

#define E_CNT 1999
#define N_PTS 2000
#define B_CNT 8
#define SEG 2048                           // X edges in [0,SEG), target edges in [SEG,2*SEG)
#define NTILES 16                          // 256-row tiles
#define NTP 136                            // upper-triangle tile pairs
#define NCH 2                              // 128-col chunks per 256-col tile
#define BLOCKS_PER_B (NTP*NCH)             // 272
#define TOTAL_BLOCKS (B_CNT*BLOCKS_PER_B)  // 2176

#define HCEXP (-2.8853900817779268f)       // -2*log2(e)
#define NEG2C (11.541560327111707f)        // +8*log2(e)

// Generate combined-edge data for slot in [0,2*SEG) of sample b:
//   A = (cx, cy, cz, u''x),  Bv = (u''y, u''z),  u'' = (t/sqrt(l)) * exp2(HCEXP*|c|^2)
// Returns diag contribution (l^2 [+ SRNF for X edges]) when wantDiag.
__device__ __forceinline__ float edge_gen(
    const float* __restrict__ outp, const float* __restrict__ tgtp,
    const float* __restrict__ tmpl, int b, int slot, bool wantDiag,
    float4& A, float2& Bv)
{
    A = make_float4(0.f, 0.f, 0.f, 0.f);
    Bv = make_float2(0.f, 0.f);
    float val = 0.f;
    bool isX = (slot < SEG);
    int e = isX ? slot : slot - SEG;
    if (e < E_CNT) {
        float ax, ay, az, bx, by, bz;
        if (isX) {
            const float* o0 = outp + ((size_t)b * N_PTS + e) * 3;
            const float* t0 = tmpl + (size_t)e * 3;
            ax = o0[0] + t0[0]; ay = o0[1] + t0[1]; az = o0[2] + t0[2];
            bx = o0[3] + t0[3]; by = o0[4] + t0[4]; bz = o0[5] + t0[5];
        } else {
            const float* g0 = tgtp + ((size_t)b * N_PTS + e) * 3;
            ax = g0[0]; ay = g0[1]; az = g0[2];
            bx = g0[3]; by = g0[4]; bz = g0[5];
        }
        float cx = 0.5f * (ax + bx), cy = 0.5f * (ay + by), cz = 0.5f * (az + bz);
        float tx = bx - ax, ty = by - ay, tz = bz - az;
        float l2 = tx * tx + ty * ty + tz * tz + 1e-12f;
        float l  = sqrtf(l2);
        float rs = rsqrtf(l);
        float f  = __builtin_amdgcn_exp2f(HCEXP * (cx * cx + cy * cy + cz * cz));
        float g  = rs * f;
        A  = make_float4(cx, cy, cz, tx * g);
        Bv = make_float2(ty * g, tz * g);
        if (wantDiag) {
            val = l * l;
            if (isX) {
                const float* t0 = tmpl + (size_t)e * 3;
                float txT = t0[3] - t0[0], tyT = t0[4] - t0[1], tzT = t0[5] - t0[2];
                float lT = sqrtf(txT * txT + tyT * tyT + tzT * tzT + 1e-12f);
                float rT = rsqrtf(lT);
                float dqx = tx * rs - txT * rT;     // q = t/sqrt(l)
                float dqy = ty * rs - tyT * rT;
                float dqz = tz * rs - tzT * rT;
                val += 1e-7f * (dqx * dqx + dqy * dqy + dqz * dqz);
            }
        }
    }
    return val;
}

// Fused edge-gen + strict-upper-triangle pair sum.  Block = 256 rows x 128
// cols; 4 waves split columns (32 each); each lane owns 4 rows (R=4).
// Rows staged ONCE per block in LDS by all 256 threads (no 4x wave
// redundancy); cols staged by threads 0..127.  Diag/SRNF computed by the
// thread that stages the row, in rt==ct && ch==0 blocks only.
// NO atomics/fences: per-block partial -> part[blockIdx]; final reduces.
__global__ __launch_bounds__(256) void fused_kernel(
    const float* __restrict__ outp, const float* __restrict__ tgtp,
    const float* __restrict__ tmpl, float* __restrict__ part)
{
    __shared__ float4 sA[128];    // col: (cx,cy,cz,u''x)
    __shared__ float2 sB[128];    // col: (u''y,u''z)
    __shared__ float4 sRA[256];   // row: (cx,cy,cz,u''x)
    __shared__ float2 sRB[256];   // row: (u''y,u''z)
    __shared__ float  red[4];

    int id = blockIdx.x;
    int b  = id / BLOCKS_PER_B;
    int r  = id % BLOCKS_PER_B;
    int t  = r >> 1, ch = r & 1;
    int rt = 0, rem = t;
    while (rem >= NTILES - rt) { rem -= NTILES - rt; ++rt; }
    int ct = rt + rem;

    int tid = threadIdx.x, lane = tid & 63, w = tid >> 6;
    int j0 = ct * 256 + ch * 128;

    // stage: every thread generates one row edge; threads <128 also one col
    bool wantDiag = (rt == ct) && (ch == 0);
    float dval;
    {
        float4 A; float2 Bv;
        dval = edge_gen(outp, tgtp, tmpl, b, rt * 256 + tid, wantDiag, A, Bv);
        sRA[tid] = A; sRB[tid] = Bv;
        if (tid < 128) {
            float4 A2; float2 B2;
            edge_gen(outp, tgtp, tmpl, b, j0 + tid, false, A2, B2);
            sA[tid] = A2; sB[tid] = B2;
        }
    }
    __syncthreads();

    // 4 rows per lane from LDS (conflict-free: lane-consecutive addresses)
    float chx[4], chy[4], chz[4], rux[4], ruy[4], ruz[4];
    int ri[4];
    #pragma unroll
    for (int k = 0; k < 4; ++k) {
        int rl = k * 64 + lane;
        ri[k] = rt * 256 + rl;
        float4 A = sRA[rl];
        float2 Bv = sRB[rl];
        chx[k] = NEG2C * A.x; chy[k] = NEG2C * A.y; chz[k] = NEG2C * A.z;
        rux[k] = A.w; ruy[k] = Bv.x; ruz[k] = Bv.y;
    }

    float av[4] = {0.f, 0.f, 0.f, 0.f};
    int jl0 = w * 32;                 // this wave's 32-column slice

    if (rt != ct) {
        #pragma unroll 4
        for (int jj = 0; jj < 32; ++jj) {
            float4 a0 = sA[jl0 + jj];
            float2 b0 = sB[jl0 + jj];
            #pragma unroll
            for (int k = 0; k < 4; ++k) {
                float arg = chx[k] * a0.x;
                arg = fmaf(chy[k], a0.y, arg);
                arg = fmaf(chz[k], a0.z, arg);
                float E = __builtin_amdgcn_exp2f(arg);
                float du = rux[k] * a0.w;
                du = fmaf(ruy[k], b0.x, du);
                du = fmaf(ruz[k], b0.y, du);
                av[k] = fmaf(E, du * du, av[k]);
            }
        }
    } else {
        #pragma unroll 4
        for (int jj = 0; jj < 32; ++jj) {
            float4 a0 = sA[jl0 + jj];
            float2 b0 = sB[jl0 + jj];
            int j = j0 + jl0 + jj;
            #pragma unroll
            for (int k = 0; k < 4; ++k) {
                float arg = chx[k] * a0.x;
                arg = fmaf(chy[k], a0.y, arg);
                arg = fmaf(chz[k], a0.z, arg);
                float E = __builtin_amdgcn_exp2f(arg);
                float du = rux[k] * a0.w;
                du = fmaf(ruy[k], b0.x, du);
                du = fmaf(ruz[k], b0.y, du);
                float m = (j > ri[k]) ? du * du : 0.f;   // strict upper
                av[k] = fmaf(E, m, av[k]);
            }
        }
    }

    // sign: same-segment tiles +, cross-segment -; x2 for symmetry.
    // dval (diag l^2 + SRNF, staged-row thread) is sign-free.
    float sgn = ((rt < 8) == (ct < 8)) ? 2.f : -2.f;
    float thr = fmaf(sgn, (av[0] + av[1]) + (av[2] + av[3]), dval);
    for (int off = 32; off; off >>= 1) thr += __shfl_down(thr, off);
    if (lane == 0) red[w] = thr;
    __syncthreads();
    if (tid == 0)
        part[id] = (red[0] + red[1]) + (red[2] + red[3]);
}

__global__ __launch_bounds__(256) void final_kernel(
    const float* __restrict__ part, float* __restrict__ outv)
{
    float s = 0.f;
    for (int i = threadIdx.x; i < TOTAL_BLOCKS; i += 256) s += part[i];
    for (int off = 32; off; off >>= 1) s += __shfl_down(s, off);
    __shared__ float red[4];
    int lane = threadIdx.x & 63, wid = threadIdx.x >> 6;
    if (lane == 0) red[wid] = s;
    __syncthreads();
    if (threadIdx.x == 0)
        outv[0] = 0.125f * ((red[0] + red[1]) + (red[2] + red[3]));
}

extern "C" void kernel_launch(void* const* d_in, const int* in_sizes, int n_in,
                              void* d_out, int out_size, void* d_ws, size_t ws_size,
                              hipStream_t stream)
{
    const float* outp = (const float*)d_in[0];  // (8,2000,3) f32
    const float* tgtp = (const float*)d_in[1];  // (8,2000,3) f32
    const float* tmpl = (const float*)d_in[3];  // (2000,3) f32
    float* part = (float*)d_ws;                 // TOTAL_BLOCKS floats, all written each launch

    fused_kernel<<<TOTAL_BLOCKS, 256, 0, stream>>>(outp, tgtp, tmpl, part);
    final_kernel<<<1, 256, 0, stream>>>(part, (float*)d_out);
}

// Round 11
// 27.687 us; speedup vs baseline: 4.0816x; 1.0431x over previous
//
#include <hip/hip_runtime.h>
#include <math.h>

#define E_CNT 1999
#define N_PTS 2000
#define B_CNT 8
#define SEG 2048                           // X edges in [0,SEG), target edges in [SEG,2*SEG)
#define NTILES 16                          // 256-row tiles
#define NTP 136                            // upper-triangle tile pairs
#define NCH 2                              // 128-col chunks per 256-col tile
#define BLOCKS_PER_B (NTP*NCH)             // 272
#define TOTAL_BLOCKS (B_CNT*BLOCKS_PER_B)  // 2176

#define HCEXP (-2.8853900817779268f)       // -2*log2(e)
#define SQRT_NEG2C 3.3972871f              // sqrt(8*log2(e))

typedef __attribute__((ext_vector_type(8))) _Float16 half8;
typedef __attribute__((ext_vector_type(4))) float f32x4;
typedef __attribute__((ext_vector_type(4))) int i32x4;

__device__ __forceinline__ half8 mk_frag(int lo, int hi) {
    i32x4 t; t[0] = lo; t[1] = hi; t[2] = 0; t[3] = 0;
    return __builtin_bit_cast(half8, t);
}

// Build the f16 edge record for slot of sample b:
//   halves [ s*cx, s*cy, s*cz, 0, u''x, u''y, u''z, 0 ],  s = sqrt(NEG2C),
//   u'' = (t/sqrt(l)) * exp2(HCEXP*|c|^2).   Pads are all-zero.
// When diagResp: returns l^2 + SRNF(X only) - selfterm, where selfterm is the
// f32 recomputation (from the ROUNDED f16 values) of what the MFMA path will
// produce for the self-pair (i,i) — cancels the in-tile diagonal exactly.
__device__ __forceinline__ float edge_rec(
    const float* __restrict__ outp, const float* __restrict__ tgtp,
    const float* __restrict__ tmpl, int b, int slot, bool diagResp,
    i32x4& rec)
{
    float val = 0.f;
    bool isX = (slot < SEG);
    int e = isX ? slot : slot - SEG;
    if (e < E_CNT) {
        float ax, ay, az, bx, by, bz;
        if (isX) {
            const float* o0 = outp + ((size_t)b * N_PTS + e) * 3;
            const float* t0 = tmpl + (size_t)e * 3;
            ax = o0[0] + t0[0]; ay = o0[1] + t0[1]; az = o0[2] + t0[2];
            bx = o0[3] + t0[3]; by = o0[4] + t0[4]; bz = o0[5] + t0[5];
        } else {
            const float* g0 = tgtp + ((size_t)b * N_PTS + e) * 3;
            ax = g0[0]; ay = g0[1]; az = g0[2];
            bx = g0[3]; by = g0[4]; bz = g0[5];
        }
        float cx = 0.5f * (ax + bx), cy = 0.5f * (ay + by), cz = 0.5f * (az + bz);
        float tx = bx - ax, ty = by - ay, tz = bz - az;
        float l2 = tx * tx + ty * ty + tz * tz + 1e-12f;
        float l  = sqrtf(l2);
        float rs = rsqrtf(l);
        float f  = __builtin_amdgcn_exp2f(HCEXP * (cx * cx + cy * cy + cz * cz));
        float g  = rs * f;
        half8 hv;
        hv[0] = (_Float16)(SQRT_NEG2C * cx);
        hv[1] = (_Float16)(SQRT_NEG2C * cy);
        hv[2] = (_Float16)(SQRT_NEG2C * cz);
        hv[3] = (_Float16)0.f;
        hv[4] = (_Float16)(tx * g);
        hv[5] = (_Float16)(ty * g);
        hv[6] = (_Float16)(tz * g);
        hv[7] = (_Float16)0.f;
        rec = __builtin_bit_cast(i32x4, hv);
        if (diagResp) {
            float a0 = (float)hv[0], a1 = (float)hv[1], a2 = (float)hv[2];
            float d0 = (float)hv[4], d1 = (float)hv[5], d2 = (float)hv[6];
            float sarg = a0 * a0 + a1 * a1 + a2 * a2;
            float sdu  = d0 * d0 + d1 * d1 + d2 * d2;
            float self = __builtin_amdgcn_exp2f(sarg) * sdu * sdu;
            val = l * l - self;
            if (isX) {
                const float* t0 = tmpl + (size_t)e * 3;
                float txT = t0[3] - t0[0], tyT = t0[4] - t0[1], tzT = t0[5] - t0[2];
                float lT = sqrtf(txT * txT + tyT * tyT + tzT * tzT + 1e-12f);
                float rT = rsqrtf(lT);
                float dqx = tx * rs - txT * rT;     // q = t/sqrt(l)
                float dqy = ty * rs - tyT * rT;
                float dqz = tz * rs - tzT * rT;
                val += 1e-7f * (dqx * dqx + dqy * dqy + dqz * dqz);
            }
        }
    } else {
        i32x4 z; z[0] = 0; z[1] = 0; z[2] = 0; z[3] = 0;
        rec = z;
    }
    return val;
}

// MFMA pair kernel.  Block = 256 rows x 128 cols of the combined signed
// measure; 16x16 pair-tiles via two mfma_f32_16x16x32_f16 (arg-dot, du-dot;
// K=32, rank 3).  Sum is invariant to A/B fragment transpose because both
// matrices are symmetric and A/B use identical records.  Per tile post:
// 4 exp2 + 4 mul + 4 fma.  Diag tiles: full sum at weight 1, self-pairs
// cancelled by edge_rec's selfterm correction.  No atomics.
__global__ __launch_bounds__(256) void fused_kernel(
    const float* __restrict__ outp, const float* __restrict__ tgtp,
    const float* __restrict__ tmpl, float* __restrict__ part)
{
    __shared__ i32x4 sRec[385];    // [0,256) rows, [256,384) cols, [384] zero
    __shared__ float red[4];

    int id = blockIdx.x;
    int b  = id / BLOCKS_PER_B;
    int r  = id % BLOCKS_PER_B;
    int t  = r >> 1, ch = r & 1;
    int rt = 0, rem = t;
    while (rem >= NTILES - rt) { rem -= NTILES - rt; ++rt; }
    int ct = rt + rem;

    int tid = threadIdx.x, lane = tid & 63, w = tid >> 6;

    // stage: each thread one row record; threads <128 one col record.
    // Self-pair (i,i) of tile row i lives in chunk ch == i/128 -> gate.
    bool diagResp = (rt == ct) && ((tid >> 7) == ch);
    i32x4 rrec;
    float dval = edge_rec(outp, tgtp, tmpl, b, rt * 256 + tid, diagResp, rrec);
    sRec[tid] = rrec;
    if (tid < 128) {
        i32x4 crec;
        edge_rec(outp, tgtp, tmpl, b, ct * 256 + ch * 128 + tid, false, crec);
        sRec[256 + tid] = crec;
    }
    if (tid == 128) {
        i32x4 z; z[0] = 0; z[1] = 0; z[2] = 0; z[3] = 0;
        sRec[384] = z;
    }
    __syncthreads();

    int l15 = lane & 15;
    bool g0 = (lane < 16);            // lanes >=16 carry k>=8 (all zero)

    // A-side records for this wave's 4 row-tiles
    i32x4 ra[4];
    #pragma unroll
    for (int q = 0; q < 4; ++q)
        ra[q] = sRec[g0 ? ((w * 4 + q) * 16 + l15) : 384];

    f32x4 av = {0.f, 0.f, 0.f, 0.f};
    #pragma unroll
    for (int ctile = 0; ctile < 8; ++ctile) {
        i32x4 rb = sRec[g0 ? (256 + ctile * 16 + l15) : 384];
        half8 bArg = mk_frag(rb[0], rb[1]);
        half8 bDu  = mk_frag(rb[2], rb[3]);
        #pragma unroll
        for (int q = 0; q < 4; ++q) {
            half8 aArg = mk_frag(ra[q][0], ra[q][1]);
            half8 aDu  = mk_frag(ra[q][2], ra[q][3]);
            f32x4 zz = {0.f, 0.f, 0.f, 0.f};
            f32x4 dA = __builtin_amdgcn_mfma_f32_16x16x32_f16(aArg, bArg, zz, 0, 0, 0);
            f32x4 dD = __builtin_amdgcn_mfma_f32_16x16x32_f16(aDu,  bDu,  zz, 0, 0, 0);
            #pragma unroll
            for (int rr = 0; rr < 4; ++rr)
                av[rr] = fmaf(__builtin_amdgcn_exp2f(dA[rr]), dD[rr] * dD[rr], av[rr]);
        }
    }

    // weights: diag tile-pair x1 (full matrix covers both triangles + diag,
    // diag cancelled by selfterm); off-diag x2; cross-segment negative.
    float sgn = (rt == ct) ? 1.f : (((rt < 8) == (ct < 8)) ? 2.f : -2.f);
    float thr = fmaf(sgn, (av[0] + av[1]) + (av[2] + av[3]), dval);
    for (int off = 32; off; off >>= 1) thr += __shfl_down(thr, off);
    if (lane == 0) red[w] = thr;
    __syncthreads();
    if (tid == 0)
        part[id] = (red[0] + red[1]) + (red[2] + red[3]);
}

__global__ __launch_bounds__(256) void final_kernel(
    const float* __restrict__ part, float* __restrict__ outv)
{
    float s = 0.f;
    for (int i = threadIdx.x; i < TOTAL_BLOCKS; i += 256) s += part[i];
    for (int off = 32; off; off >>= 1) s += __shfl_down(s, off);
    __shared__ float red[4];
    int lane = threadIdx.x & 63, wid = threadIdx.x >> 6;
    if (lane == 0) red[wid] = s;
    __syncthreads();
    if (threadIdx.x == 0)
        outv[0] = 0.125f * ((red[0] + red[1]) + (red[2] + red[3]));
}

extern "C" void kernel_launch(void* const* d_in, const int* in_sizes, int n_in,
                              void* d_out, int out_size, void* d_ws, size_t ws_size,
                              hipStream_t stream)
{
    const float* outp = (const float*)d_in[0];  // (8,2000,3) f32
    const float* tgtp = (const float*)d_in[1];  // (8,2000,3) f32
    const float* tmpl = (const float*)d_in[3];  // (2000,3) f32
    float* part = (float*)d_ws;                 // TOTAL_BLOCKS floats, all written each launch

    fused_kernel<<<TOTAL_BLOCKS, 256, 0, stream>>>(outp, tgtp, tmpl, part);
    final_kernel<<<1, 256, 0, stream>>>(part, (float*)d_out);
}